// Round 1
// baseline (947.523 us; speedup 1.0000x reference)
//
#include <hip/hip_runtime.h>

// SpectralConv2d: B=16, CIN=COUT=64, H=W=256, M1=M2=32
// Decomposition:
//  k1: Xw[bi,h,j]   = sum_w x[bi,h,w] * Fw[w,j]          (j<32: cos, j>=32: -sin)   [real W-DFT, 32 modes]
//  k2: Xf[bi,p,ky,kx]= sum_h Xw[bi,h,(p,kx)] * e^{-2pi i ky h/256}                   [H-DFT]
//  k3: Y[b,o,...]   = sum_i Xf[b,i,...] * (wr + i wi)                               [channel mix]
//  k4: T[bo,h,p,kx] = (c_kx/65536) * sum_ky Y[bo,ky,kx] * e^{+2pi i ky h/256}       [H-iDFT]
//  k5: out[bo,h,w]  = sum_kx Tr*cos(2pi kx w/256) - Ti*sin(...)                     [W-iDFT, real]
// Workspace (floats): Xw @0 (16777216), Xf @16777216 (2097152), Y @18874368 (2097152), T aliases Xw.

#define TPB 256
static constexpr float ANG = 0.02454369260617026f; // 2*pi/256

// ------------------------- Stage 1: W-DFT -------------------------
__launch_bounds__(TPB)
__global__ void k1_wdft(const float* __restrict__ x, float* __restrict__ Xw) {
    __shared__ float tab[256];
    __shared__ float Bm[256][64];   // twiddle matrix, 64KB
    __shared__ float As[32][64];    // A chunk transposed [k][m], 8KB
    const int t = threadIdx.x;
    tab[t] = cosf((float)t * ANG);
    __syncthreads();
    for (int r = 0; r < 64; ++r) {  // fill 256x64 twiddles from table
        int idx = r * 256 + t;
        int k = idx >> 6, j = idx & 63;
        Bm[k][j] = (j < 32) ? tab[(k * j) & 255] : -tab[(k * (j - 32) + 192) & 255];
    }
    const int ty = t >> 4, tx = t & 15;
    const long row0 = (long)blockIdx.x * 64;
    const float* xblk = x + row0 * 256;
    float acc[4][4];
    #pragma unroll
    for (int r = 0; r < 4; ++r)
        #pragma unroll
        for (int c = 0; c < 4; ++c) acc[r][c] = 0.f;

    for (int kc = 0; kc < 8; ++kc) {
        __syncthreads();
        #pragma unroll
        for (int rep = 0; rep < 2; ++rep) {
            int idx = rep * 256 + t;          // 0..511
            int m = idx & 63, kq = idx >> 6;  // kq 0..7
            float4 v = *(const float4*)(xblk + (long)m * 256 + kc * 32 + kq * 4);
            As[kq * 4 + 0][m] = v.x;
            As[kq * 4 + 1][m] = v.y;
            As[kq * 4 + 2][m] = v.z;
            As[kq * 4 + 3][m] = v.w;
        }
        __syncthreads();
        #pragma unroll
        for (int kk = 0; kk < 32; ++kk) {
            const float4 av = *(const float4*)&As[kk][ty * 4];
            const float4 bv = *(const float4*)&Bm[kc * 32 + kk][tx * 4];
            const float a[4] = {av.x, av.y, av.z, av.w};
            const float b[4] = {bv.x, bv.y, bv.z, bv.w};
            #pragma unroll
            for (int r = 0; r < 4; ++r)
                #pragma unroll
                for (int c = 0; c < 4; ++c)
                    acc[r][c] = fmaf(a[r], b[c], acc[r][c]);
        }
    }
    float* dst = Xw + row0 * 64;
    #pragma unroll
    for (int r = 0; r < 4; ++r) {
        *(float4*)(dst + (long)(ty * 4 + r) * 64 + tx * 4) =
            make_float4(acc[r][0], acc[r][1], acc[r][2], acc[r][3]);
    }
}

// ------------------------- Stage 2: H-DFT -------------------------
__launch_bounds__(TPB)
__global__ void k2_hdft(const float* __restrict__ Xw, float* __restrict__ Xf) {
    __shared__ float tab[256];
    __shared__ float Xs[256][64];   // 64KB: [h][j]
    const int t = threadIdx.x;
    tab[t] = cosf((float)t * ANG);
    const float4* src = (const float4*)(Xw + (long)blockIdx.x * 16384);
    float4* d4 = (float4*)Xs;
    #pragma unroll
    for (int q = 0; q < 16; ++q) d4[q * 256 + t] = src[q * 256 + t];
    __syncthreads();
    const int ky = t >> 3, kxq = t & 7;
    float ar[4] = {0.f, 0.f, 0.f, 0.f}, ai[4] = {0.f, 0.f, 0.f, 0.f};
    int mh = 0;  // (ky*h) & 255, exact integer recurrence
    #pragma unroll 4
    for (int h = 0; h < 256; ++h) {
        const float c = tab[mh];
        const float s = tab[(mh + 192) & 255];
        mh = (mh + ky) & 255;
        const float4 xr4 = *(const float4*)&Xs[h][kxq * 4];
        const float4 xi4 = *(const float4*)&Xs[h][32 + kxq * 4];
        const float xr[4] = {xr4.x, xr4.y, xr4.z, xr4.w};
        const float xi[4] = {xi4.x, xi4.y, xi4.z, xi4.w};
        #pragma unroll
        for (int q = 0; q < 4; ++q) {   // (xr+i·xi)*(c - i·s)
            ar[q] = fmaf(xr[q], c, ar[q]);
            ar[q] = fmaf(xi[q], s, ar[q]);
            ai[q] = fmaf(xi[q], c, ai[q]);
            ai[q] = fmaf(-xr[q], s, ai[q]);
        }
    }
    float* dst = Xf + (long)blockIdx.x * 2048 + ky * 32 + kxq * 4;
    *(float4*)dst          = make_float4(ar[0], ar[1], ar[2], ar[3]);
    *(float4*)(dst + 1024) = make_float4(ai[0], ai[1], ai[2], ai[3]);
}

// ------------------------- Stage 3: channel mix -------------------------
__launch_bounds__(TPB)
__global__ void k3_mix(const float* __restrict__ Xf, const float* __restrict__ wr,
                       const float* __restrict__ wi, float* __restrict__ Y) {
    __shared__ float xf_s[16 * 36]; // (b,p) rows, padded stride 36
    __shared__ float w_s[32 * 36];  // (oo,p) rows
    const int t = threadIdx.x;
    const int bk = blockIdx.x;
    const int ky = bk & 31, ot = (bk >> 5) & 3, bh = bk >> 7;
    const int o0 = ot * 16, b0 = bh * 8;
    const int oo = t >> 4, bb = (t >> 1) & 7, half = t & 1;
    float ar[16], ai[16];
    #pragma unroll
    for (int q = 0; q < 16; ++q) { ar[q] = 0.f; ai[q] = 0.f; }

    for (int i = 0; i < 64; ++i) {
        __syncthreads();
        if (t < 128) {
            int run = t >> 3, kxq = t & 7;
            int b = run >> 1, p = run & 1;
            float4 v = *(const float4*)(Xf + (long)((b0 + b) * 64 + i) * 2048 + p * 1024 + ky * 32 + kxq * 4);
            *(float4*)&xf_s[(b * 2 + p) * 36 + kxq * 4] = v;
        }
        {
            int oo2 = t >> 4, p = (t >> 3) & 1, kxq = t & 7;
            const float* wsrc = p ? wi : wr;
            float4 v = *(const float4*)(wsrc + (long)(i * 64 + o0 + oo2) * 1024 + ky * 32 + kxq * 4);
            *(float4*)&w_s[(oo2 * 2 + p) * 36 + kxq * 4] = v;
        }
        __syncthreads();
        const float* xfr = &xf_s[(bb * 2 + 0) * 36 + half * 16];
        const float* xfi = &xf_s[(bb * 2 + 1) * 36 + half * 16];
        const float* wre = &w_s[(oo * 2 + 0) * 36 + half * 16];
        const float* wim = &w_s[(oo * 2 + 1) * 36 + half * 16];
        #pragma unroll
        for (int q = 0; q < 4; ++q) {
            const float4 xr4 = *(const float4*)(xfr + q * 4);
            const float4 xi4 = *(const float4*)(xfi + q * 4);
            const float4 wr4 = *(const float4*)(wre + q * 4);
            const float4 wi4 = *(const float4*)(wim + q * 4);
            const float xr[4] = {xr4.x, xr4.y, xr4.z, xr4.w};
            const float xi[4] = {xi4.x, xi4.y, xi4.z, xi4.w};
            const float wrr[4] = {wr4.x, wr4.y, wr4.z, wr4.w};
            const float wii[4] = {wi4.x, wi4.y, wi4.z, wi4.w};
            #pragma unroll
            for (int u = 0; u < 4; ++u) {   // (x)*(w) complex
                ar[q * 4 + u] = fmaf(xr[u], wrr[u], ar[q * 4 + u]);
                ar[q * 4 + u] = fmaf(-xi[u], wii[u], ar[q * 4 + u]);
                ai[q * 4 + u] = fmaf(xr[u], wii[u], ai[q * 4 + u]);
                ai[q * 4 + u] = fmaf(xi[u], wrr[u], ai[q * 4 + u]);
            }
        }
    }
    const long ybase = (long)((b0 + bb) * 64 + (o0 + oo)) * 2048 + ky * 32 + half * 16;
    #pragma unroll
    for (int q = 0; q < 4; ++q) {
        *(float4*)(Y + ybase + q * 4)        = make_float4(ar[q*4], ar[q*4+1], ar[q*4+2], ar[q*4+3]);
        *(float4*)(Y + ybase + 1024 + q * 4) = make_float4(ai[q*4], ai[q*4+1], ai[q*4+2], ai[q*4+3]);
    }
}

// ------------------------- Stage 4: H-iDFT -------------------------
__launch_bounds__(TPB)
__global__ void k4_hidft(const float* __restrict__ Y, float* __restrict__ T) {
    __shared__ float tab[256];
    __shared__ float Ys[2048];
    const int t = threadIdx.x;
    tab[t] = cosf((float)t * ANG);
    const float4* src = (const float4*)(Y + (long)blockIdx.x * 2048);
    float4* d4 = (float4*)Ys;
    d4[t] = src[t];
    d4[256 + t] = src[256 + t];
    __syncthreads();
    const int h = t;
    float Tr[32], Ti[32];
    #pragma unroll
    for (int q = 0; q < 32; ++q) { Tr[q] = 0.f; Ti[q] = 0.f; }
    int mh = 0;  // (ky*h) & 255
    for (int ky = 0; ky < 32; ++ky) {
        const float c = tab[mh];
        const float s = tab[(mh + 192) & 255];
        mh = (mh + h) & 255;
        #pragma unroll
        for (int q = 0; q < 8; ++q) {
            const float4 yr4 = *(const float4*)&Ys[ky * 32 + q * 4];
            const float4 yi4 = *(const float4*)&Ys[1024 + ky * 32 + q * 4];
            const float yr[4] = {yr4.x, yr4.y, yr4.z, yr4.w};
            const float yi[4] = {yi4.x, yi4.y, yi4.z, yi4.w};
            #pragma unroll
            for (int u = 0; u < 4; ++u) {   // (y)*(c + i s)
                Tr[q*4+u] = fmaf(yr[u], c, Tr[q*4+u]);
                Tr[q*4+u] = fmaf(-yi[u], s, Tr[q*4+u]);
                Ti[q*4+u] = fmaf(yr[u], s, Ti[q*4+u]);
                Ti[q*4+u] = fmaf(yi[u], c, Ti[q*4+u]);
            }
        }
    }
    #pragma unroll
    for (int q = 0; q < 32; ++q) {
        const float mm = (q == 0) ? (1.f / 65536.f) : (2.f / 65536.f);
        Tr[q] *= mm; Ti[q] *= mm;
    }
    float* dst = T + (long)blockIdx.x * 16384 + h * 64;
    #pragma unroll
    for (int q = 0; q < 8; ++q) {
        *(float4*)(dst + q * 4)      = make_float4(Tr[q*4], Tr[q*4+1], Tr[q*4+2], Tr[q*4+3]);
        *(float4*)(dst + 32 + q * 4) = make_float4(Ti[q*4], Ti[q*4+1], Ti[q*4+2], Ti[q*4+3]);
    }
}

// ------------------------- Stage 5: W-iDFT -------------------------
__launch_bounds__(TPB)
__global__ void k5_widft(const float* __restrict__ T, float* __restrict__ out) {
    __shared__ float tab[256];
    __shared__ float As[64][64];   // [k][m] transposed, 16KB
    __shared__ float Gs[16][256];  // twiddle chunk, 16KB
    const int t = threadIdx.x;
    tab[t] = cosf((float)t * ANG);
    const long row0 = (long)blockIdx.x * 64;
    const float* tblk = T + row0 * 64;
    #pragma unroll
    for (int rep = 0; rep < 4; ++rep) {
        int idx = rep * 256 + t;           // 0..1023
        int m = idx & 63, kq = idx >> 6;   // kq 0..15
        float4 v = *(const float4*)(tblk + (long)m * 64 + kq * 4);
        As[kq * 4 + 0][m] = v.x;
        As[kq * 4 + 1][m] = v.y;
        As[kq * 4 + 2][m] = v.z;
        As[kq * 4 + 3][m] = v.w;
    }
    const int ty = t >> 4, tx = t & 15;
    float acc[4][16];
    #pragma unroll
    for (int r = 0; r < 4; ++r)
        #pragma unroll
        for (int c = 0; c < 16; ++c) acc[r][c] = 0.f;

    for (int kc = 0; kc < 4; ++kc) {
        __syncthreads();   // tab/As visible; prev compute done before Gs overwrite
        #pragma unroll
        for (int r = 0; r < 16; ++r) {
            int idx = r * 256 + t;
            int kk = idx >> 8, w = idx & 255;
            int k = kc * 16 + kk;
            Gs[kk][w] = (k < 32) ? tab[(k * w) & 255] : -tab[((k - 32) * w + 192) & 255];
        }
        __syncthreads();
        #pragma unroll
        for (int kk = 0; kk < 16; ++kk) {
            const float4 av = *(const float4*)&As[kc * 16 + kk][ty * 4];
            const float a[4] = {av.x, av.y, av.z, av.w};
            #pragma unroll
            for (int u = 0; u < 4; ++u) {
                const float4 bv = *(const float4*)&Gs[kk][u * 64 + tx * 4];
                const float b[4] = {bv.x, bv.y, bv.z, bv.w};
                #pragma unroll
                for (int r = 0; r < 4; ++r)
                    #pragma unroll
                    for (int c = 0; c < 4; ++c)
                        acc[r][u * 4 + c] = fmaf(a[r], b[c], acc[r][u * 4 + c]);
            }
        }
    }
    float* outp = out + row0 * 256;
    #pragma unroll
    for (int r = 0; r < 4; ++r)
        #pragma unroll
        for (int u = 0; u < 4; ++u)
            *(float4*)(outp + (long)(ty * 4 + r) * 256 + u * 64 + tx * 4) =
                make_float4(acc[r][u*4], acc[r][u*4+1], acc[r][u*4+2], acc[r][u*4+3]);
}

extern "C" void kernel_launch(void* const* d_in, const int* in_sizes, int n_in,
                              void* d_out, int out_size, void* d_ws, size_t ws_size,
                              hipStream_t stream) {
    (void)in_sizes; (void)n_in; (void)out_size; (void)ws_size;
    const float* x  = (const float*)d_in[0];
    const float* wr = (const float*)d_in[1];
    const float* wi = (const float*)d_in[2];
    float* out = (float*)d_out;
    float* ws  = (float*)d_ws;
    float* Xw = ws;                 // 16777216 floats (64 MiB)
    float* Xf = ws + 16777216;      // 2097152 floats
    float* Y  = ws + 18874368;      // 2097152 floats
    float* T  = ws;                 // aliases Xw (Xw dead after k2)

    k1_wdft <<<dim3(4096), dim3(TPB), 0, stream>>>(x, Xw);
    k2_hdft <<<dim3(1024), dim3(TPB), 0, stream>>>(Xw, Xf);
    k3_mix  <<<dim3(256),  dim3(TPB), 0, stream>>>(Xf, wr, wi, Y);
    k4_hidft<<<dim3(1024), dim3(TPB), 0, stream>>>(Y, T);
    k5_widft<<<dim3(4096), dim3(TPB), 0, stream>>>(T, out);
}